// Round 5
// baseline (574.384 us; speedup 1.0000x reference)
//
#include <hip/hip_runtime.h>

typedef __bf16 bf16x8 __attribute__((ext_vector_type(8)));
typedef float f32x4 __attribute__((ext_vector_type(4)));

union U8 { uint4 u; bf16x8 b; };

__device__ inline float bf16f(unsigned short h) {
    return __uint_as_float(((unsigned)h) << 16);
}

__device__ inline unsigned short f32_to_bf16_rn(float f) {
    unsigned u = __float_as_uint(f);
    unsigned rounding = 0x7FFFu + ((u >> 16) & 1u);
    u += rounding;
    return (unsigned short)(u >> 16);
}

__device__ inline double wsum(double v) {
    #pragma unroll
    for (int m = 32; m; m >>= 1) v += __shfl_xor(v, m, 64);
    return v;
}
__device__ inline double wmin(double v) {
    #pragma unroll
    for (int m = 32; m; m >>= 1) v = fmin(v, __shfl_xor(v, m, 64));
    return v;
}
__device__ inline double wmax(double v) {
    #pragma unroll
    for (int m = 32; m; m >>= 1) v = fmax(v, __shfl_xor(v, m, 64));
    return v;
}

// ---------------------------------------------------------------------------
// Full-wave (64-lane) fp64 sum on the VALU pipe only (DPP butterflies +
// row broadcasts), result broadcast to all lanes via readlane.
// Validated on-device in rounds 3/4 (bit-identical absmax).
// ---------------------------------------------------------------------------
__device__ inline double dpp_sum64(double v) {
    union DU { double d; int i[2]; };
    DU x, t; x.d = v;
    t.i[0] = __builtin_amdgcn_update_dpp(0, x.i[0], 0xB1, 0xF, 0xF, true);
    t.i[1] = __builtin_amdgcn_update_dpp(0, x.i[1], 0xB1, 0xF, 0xF, true);
    x.d += t.d;
    t.i[0] = __builtin_amdgcn_update_dpp(0, x.i[0], 0x4E, 0xF, 0xF, true);
    t.i[1] = __builtin_amdgcn_update_dpp(0, x.i[1], 0x4E, 0xF, 0xF, true);
    x.d += t.d;
    t.i[0] = __builtin_amdgcn_update_dpp(0, x.i[0], 0x141, 0xF, 0xF, true);
    t.i[1] = __builtin_amdgcn_update_dpp(0, x.i[1], 0x141, 0xF, 0xF, true);
    x.d += t.d;
    t.i[0] = __builtin_amdgcn_update_dpp(0, x.i[0], 0x140, 0xF, 0xF, true);
    t.i[1] = __builtin_amdgcn_update_dpp(0, x.i[1], 0x140, 0xF, 0xF, true);
    x.d += t.d;
    t.i[0] = __builtin_amdgcn_update_dpp(0, x.i[0], 0x142, 0xF, 0xF, true);
    t.i[1] = __builtin_amdgcn_update_dpp(0, x.i[1], 0x142, 0xF, 0xF, true);
    x.d += t.d;
    t.i[0] = __builtin_amdgcn_update_dpp(0, x.i[0], 0x143, 0xF, 0xF, true);
    t.i[1] = __builtin_amdgcn_update_dpp(0, x.i[1], 0x143, 0xF, 0xF, true);
    x.d += t.d;
    int lo = __builtin_amdgcn_readlane(x.i[0], 63);
    int hi = __builtin_amdgcn_readlane(x.i[1], 63);
    return __hiloint2double(hi, lo);
}

// wave-uniform fp64 broadcast from lane l (compile-time or uniform l), VALU-only
__device__ inline double rdlaned(double v, int l) {
    union DU { double d; int i[2]; };
    DU u; u.d = v;
    int lo = __builtin_amdgcn_readlane(u.i[0], l);
    int hi = __builtin_amdgcn_readlane(u.i[1], l);
    return __hiloint2double(hi, lo);
}

__device__ inline float4 f4add(float4 a, float4 b) {
    return float4{a.x + b.x, a.y + b.y, a.z + b.z, a.w + b.w};
}

#define AS1C(p) ((const __attribute__((address_space(1))) void*)(p))
#define AS3(p)  ((__attribute__((address_space(3))) void*)(p))

// ---------------------------------------------------------------------------
// Kernel 0: split X into 3 bf16 planes; build PACKED-SYMMETRIC W planes
// (upper triangle incl. diagonal, row-major by i: 2080 real rows + 32 pad)
// and symmetric bias (reg folded into diagonal).
// packed p -> (i,j), i<=j ; start(i) = i*(129-i)/2.
// ---------------------------------------------------------------------------
__global__ __launch_bounds__(256) void split2(
    const float* __restrict__ X, const float* __restrict__ W,
    const float* __restrict__ b, const float* __restrict__ regp,
    unsigned short* __restrict__ Xh, unsigned short* __restrict__ Xm, unsigned short* __restrict__ Xl,
    unsigned short* __restrict__ Sh, unsigned short* __restrict__ Sm, unsigned short* __restrict__ Sl,
    float* __restrict__ bsym)
{
    size_t i4 = (size_t)blockIdx.x * 256 + threadIdx.x;   // total 2129920 float4 items

    if (i4 < 1048576) {                                    // X part: 2048x2048 / 4
        float4 v = ((const float4*)X)[i4];
        ushort4 h, m, l; float r1;
        h.x = f32_to_bf16_rn(v.x); r1 = v.x - bf16f(h.x);
        m.x = f32_to_bf16_rn(r1);  l.x = f32_to_bf16_rn(r1 - bf16f(m.x));
        h.y = f32_to_bf16_rn(v.y); r1 = v.y - bf16f(h.y);
        m.y = f32_to_bf16_rn(r1);  l.y = f32_to_bf16_rn(r1 - bf16f(m.y));
        h.z = f32_to_bf16_rn(v.z); r1 = v.z - bf16f(h.z);
        m.z = f32_to_bf16_rn(r1);  l.z = f32_to_bf16_rn(r1 - bf16f(m.z));
        h.w = f32_to_bf16_rn(v.w); r1 = v.w - bf16f(h.w);
        m.w = f32_to_bf16_rn(r1);  l.w = f32_to_bf16_rn(r1 - bf16f(m.w));
        ((ushort4*)Xh)[i4] = h;
        ((ushort4*)Xm)[i4] = m;
        ((ushort4*)Xl)[i4] = l;
        return;
    }

    size_t q = i4 - 1048576;                               // 2112 rows x 512 float4
    int p  = (int)(q >> 9);
    int d4 = (int)(q & 511);

    if (p >= 2080) {                                       // pad rows: zeros
        ushort4 z; z.x = 0; z.y = 0; z.z = 0; z.w = 0;
        ((ushort4*)Sh)[q] = z; ((ushort4*)Sm)[q] = z; ((ushort4*)Sl)[q] = z;
        if (d4 == 0) bsym[p] = 0.0f;
        return;
    }

    // invert packed index: i = floor((129 - sqrt(129^2 - 8p))/2), then fixup
    double sd = sqrt(16641.0 - 8.0 * (double)p);
    int i = (int)((129.0 - sd) * 0.5);
    if (i < 0) i = 0;
    if (i > 63) i = 63;
    while (i < 63 && ((i + 1) * (128 - i)) / 2 <= p) ++i;
    while (i > 0 && (i * (129 - i)) / 2 > p) --i;
    int j = i + (p - (i * (129 - i)) / 2);
    int e1 = i * 64 + j;
    int e2 = j * 64 + i;

    float4 v1 = ((const float4*)W)[(size_t)e1 * 512 + d4];
    float4 v2 = ((const float4*)W)[(size_t)e2 * 512 + d4];
    float4 v;
    v.x = 0.5f * (v1.x + v2.x);
    v.y = 0.5f * (v1.y + v2.y);
    v.z = 0.5f * (v1.z + v2.z);
    v.w = 0.5f * (v1.w + v2.w);

    ushort4 h, m, l; float r1;
    h.x = f32_to_bf16_rn(v.x); r1 = v.x - bf16f(h.x);
    m.x = f32_to_bf16_rn(r1);  l.x = f32_to_bf16_rn(r1 - bf16f(m.x));
    h.y = f32_to_bf16_rn(v.y); r1 = v.y - bf16f(h.y);
    m.y = f32_to_bf16_rn(r1);  l.y = f32_to_bf16_rn(r1 - bf16f(m.y));
    h.z = f32_to_bf16_rn(v.z); r1 = v.z - bf16f(h.z);
    m.z = f32_to_bf16_rn(r1);  l.z = f32_to_bf16_rn(r1 - bf16f(m.z));
    h.w = f32_to_bf16_rn(v.w); r1 = v.w - bf16f(h.w);
    m.w = f32_to_bf16_rn(r1);  l.w = f32_to_bf16_rn(r1 - bf16f(m.w));
    ((ushort4*)Sh)[q] = h;
    ((ushort4*)Sm)[q] = m;
    ((ushort4*)Sl)[q] = l;

    if (d4 == 0)
        bsym[p] = 0.5f * (b[e1] + b[e2]) + ((i == j) ? regp[0] : 0.0f);
}

// ---------------------------------------------------------------------------
// Kernel 1: 6-plane bf16 GEMM over PACKED columns, SPLIT-K x2.
// 1056 blocks (= 8 XCD x 132), each does half of K into its own Mp half.
// 128x64 tiles, 36 KB LDS, bijective XCD swizzle per K-half.
// ---------------------------------------------------------------------------
__global__ __launch_bounds__(256) void gemm_packed(
    const unsigned short* __restrict__ Xh, const unsigned short* __restrict__ Xm,
    const unsigned short* __restrict__ Xl,
    const unsigned short* __restrict__ Sh, const unsigned short* __restrict__ Sm,
    const unsigned short* __restrict__ Sl,
    const float* __restrict__ bsym, float* __restrict__ Mp)
{
    const int K = 2048, NP = 2112;
    __shared__ unsigned short S[18432];   // 36 KB

    int tid  = threadIdx.x;
    int id   = blockIdx.x;                 // 0..1055
    int c    = id & 7;                     // XCD (hw round-robins id%8)
    int sid  = id >> 3;                    // 0..131
    int kh   = (sid >= 66) ? 1 : 0;        // K-half
    int sidh = sid - kh * 66;              // 0..65
    int wg   = c * 66 + sidh;              // bijective within each K-half
    int bx   = wg % 33;                    // 0..32 packed-col tile
    int by   = wg / 33;                    // 0..15
    int m0   = by * 128;
    int n0   = bx * 64;
    int kb   = kh * 1024;

    int wave = tid >> 6;
    int lane = tid & 63;
    int l16  = lane & 15;
    int quad = lane >> 4;
    int wm   = wave * 32;

    const unsigned short* gpA[3];
    const unsigned short* gpB[3];
    gpA[0] = Xh + (size_t)m0 * K;
    gpA[1] = Xm + (size_t)m0 * K;
    gpA[2] = Xl + (size_t)m0 * K;
    gpB[0] = Sh + (size_t)n0 * K;
    gpB[1] = Sm + (size_t)n0 * K;
    gpB[2] = Sl + (size_t)n0 * K;

    int rA = lane >> 2;              // 0..15
    int cA = (lane & 3) << 3;        // ushort col offset 0,8,16,24

    f32x4 acc[2][4];
    #pragma unroll
    for (int mi = 0; mi < 2; ++mi)
        #pragma unroll
        for (int ni = 0; ni < 4; ++ni)
            acc[mi][ni] = f32x4{0.f, 0.f, 0.f, 0.f};

    for (int k0 = kb; k0 < kb + 1024; k0 += 32) {
        __syncthreads();
        #pragma unroll
        for (int p = 0; p < 3; ++p) {
            #pragma unroll
            for (int q = 0; q < 2; ++q) {
                const unsigned short* g = gpA[p] + (size_t)(32 * wave + 16 * q + rA) * K + k0 + cA;
                char* l = (char*)S + p * 8192 + wave * 2048 + q * 1024;
                __builtin_amdgcn_global_load_lds(AS1C(g), AS3(l), 16, 0, 0);
            }
            {
                const unsigned short* g = gpB[p] + (size_t)(16 * wave + rA) * K + k0 + cA;
                char* l = (char*)S + 24576 + p * 4096 + wave * 1024;
                __builtin_amdgcn_global_load_lds(AS1C(g), AS3(l), 16, 0, 0);
            }
        }
        __syncthreads();

        U8 ah[2], am[2], al[2], bh[4], bm[4], bl[4];
        #pragma unroll
        for (int mi = 0; mi < 2; ++mi) {
            int ro = (wm + mi * 16 + l16) * 32 + quad * 8;
            ah[mi].u = *(const uint4*)&S[ro];
            am[mi].u = *(const uint4*)&S[4096 + ro];
            al[mi].u = *(const uint4*)&S[8192 + ro];
        }
        #pragma unroll
        for (int ni = 0; ni < 4; ++ni) {
            int ro = (ni * 16 + l16) * 32 + quad * 8;
            bh[ni].u = *(const uint4*)&S[12288 + ro];
            bm[ni].u = *(const uint4*)&S[14336 + ro];
            bl[ni].u = *(const uint4*)&S[16384 + ro];
        }

        #pragma unroll
        for (int mi = 0; mi < 2; ++mi)
            #pragma unroll
            for (int ni = 0; ni < 4; ++ni) {
                acc[mi][ni] = __builtin_amdgcn_mfma_f32_16x16x32_bf16(
                    al[mi].b, bh[ni].b, acc[mi][ni], 0, 0, 0);
                acc[mi][ni] = __builtin_amdgcn_mfma_f32_16x16x32_bf16(
                    ah[mi].b, bl[ni].b, acc[mi][ni], 0, 0, 0);
                acc[mi][ni] = __builtin_amdgcn_mfma_f32_16x16x32_bf16(
                    am[mi].b, bm[ni].b, acc[mi][ni], 0, 0, 0);
                acc[mi][ni] = __builtin_amdgcn_mfma_f32_16x16x32_bf16(
                    am[mi].b, bh[ni].b, acc[mi][ni], 0, 0, 0);
                acc[mi][ni] = __builtin_amdgcn_mfma_f32_16x16x32_bf16(
                    ah[mi].b, bm[ni].b, acc[mi][ni], 0, 0, 0);
                acc[mi][ni] = __builtin_amdgcn_mfma_f32_16x16x32_bf16(
                    ah[mi].b, bh[ni].b, acc[mi][ni], 0, 0, 0);
            }
    }

    float* Mout = Mp + (size_t)kh * 4325376;   // 2048*2112 floats per half
    #pragma unroll
    for (int ni = 0; ni < 4; ++ni) {
        int col = n0 + ni * 16 + l16;
        float bv = kh ? 0.0f : bsym[col];
        #pragma unroll
        for (int mi = 0; mi < 2; ++mi) {
            int row = m0 + wm + mi * 16 + quad * 4;
            #pragma unroll
            for (int r = 0; r < 4; ++r)
                Mout[(size_t)(row + r) * NP + col] = acc[mi][ni][r] + bv;
        }
    }
}

// ---------------------------------------------------------------------------
// Kernel 2 (v5): FUSED fp64 Householder tridiag + Sturm bisection.
// Tridiag part = proven v4 (2-wave column-split, dpp reductions, barrier-free
// phase 2). New: wave 1 continues into bisection with the Sturm inner loop on
// readlane broadcasts (pure VALU, zero LDS) -> blocks in bisect phase overlap
// the LDS-bound tridiag phase of co-resident blocks on disjoint pipes.
// Writes eigenvalue outputs directly (no trid round-trip, no 4th launch).
// ---------------------------------------------------------------------------
__global__ __launch_bounds__(128, 4) void tridiag_bisect(
    const float* __restrict__ Mp, float* __restrict__ out)
{
    __shared__ __align__(16) float Ls[2112];           // packed row (8.25 KB)
    __shared__ __align__(16) double rowb[64];          // row k (= col k) dump
    __shared__ __align__(16) double ubuf[64];
    __shared__ __align__(16) double wbuf[64];
    __shared__ __align__(16) double pps[128];          // p partials per wave
    __shared__ double dbuf[64];
    __shared__ double ebuf[64];

    int g   = blockIdx.x;
    int tid = threadIdx.x;
    int h   = tid >> 6;                                // wave 0/1
    int t   = tid & 63;                                // row index
    int base = 32 * h;                                 // first owned column

    const float4* Pg0 = (const float4*)(Mp + (size_t)g * 2112);
    const float4* Pg1 = (const float4*)(Mp + 4325376 + (size_t)g * 2112);
    float4* L4 = (float4*)Ls;
    #pragma unroll
    for (int s = 0; s < 4; ++s)
        L4[s * 128 + tid] = f4add(Pg0[s * 128 + tid], Pg1[s * 128 + tid]);
    if (tid < 16) L4[512 + tid] = f4add(Pg0[512 + tid], Pg1[512 + tid]);
    __syncthreads();

    // lane (h,t): row t, columns base..base+31 from packed upper triangle
    double A[32];
    #pragma unroll
    for (int jj = 0; jj < 32; ++jj) {
        int cj = base + jj;
        int lo = (t < cj) ? t : cj;
        int hi = t + cj - lo;
        int idx = ((lo * (129 - lo)) >> 1) + (hi - lo);
        A[jj] = (double)Ls[idx];
    }

    // ---- phase 1: k = 0..31, both waves active, 4 barriers/iter ---------
    #pragma unroll 1
    for (int k = 0; k < 32; ++k) {
        if (t == k) {                                  // dump own half of row k
            #pragma unroll
            for (int jj = 0; jj < 16; ++jj)
                *(double2*)&rowb[base + 2 * jj] = double2{A[2 * jj], A[2 * jj + 1]};
        }
        __syncthreads();                               // B1

        double x  = rowb[t];
        double x1 = rowb[k + 1];
        double xm = (t > k) ? x : 0.0;
        double sigma = dpp_sum64(xm * xm);             // VALU-pipe reduction

        double alpha = 0.0, u = 0.0, w = 0.0, rK = 0.0;
        bool run = (sigma > 1e-300);                   // uniform
        if (run) {
            double sq = sqrt(sigma);
            alpha = (x1 >= 0.0) ? -sq : sq;
            rK = 1.0 / (sigma - x1 * alpha);
            u = (t == k + 1) ? (x - alpha) : xm;
        }
        if (h == 0) ubuf[t] = u;
        if (tid == 0) { dbuf[k] = rowb[k]; ebuf[k] = alpha; }
        __syncthreads();                               // B2

        double ph = 0.0;
        if (run) {
            double p0 = 0.0, p1 = 0.0;
            #pragma unroll
            for (int jj = 0; jj < 16; ++jj) {
                double2 uv = *(const double2*)&ubuf[base + 2 * jj];
                p0 += A[2 * jj]     * uv.x;
                p1 += A[2 * jj + 1] * uv.y;
            }
            ph = p0 + p1;
        }
        pps[h * 64 + t] = ph;
        __syncthreads();                               // B3

        if (run) {
            double p = (t > k) ? (pps[t] + pps[64 + t]) * rK : 0.0;
            double cc = dpp_sum64(u * p) * (0.5 * rK); // VALU-pipe reduction
            w = p - cc * u;
        }
        if (h == 0) wbuf[t] = w;
        __syncthreads();                               // B4

        if (run) {
            #pragma unroll
            for (int jj = 0; jj < 16; ++jj) {
                double2 uv = *(const double2*)&ubuf[base + 2 * jj];
                double2 wv = *(const double2*)&wbuf[base + 2 * jj];
                A[2 * jj]     -= u * wv.x + w * uv.x;
                A[2 * jj + 1] -= u * wv.y + w * uv.y;
            }
        }
    }

    // wave 0's columns are frozen from here; it exits. No further barriers.
    if (h == 0) return;

    // ---- phase 2: k = 32..61, wave 1 only, barrier-free -----------------
    #pragma unroll 1
    for (int k = 32; k < 62; ++k) {
        if (t == k) {
            #pragma unroll
            for (int jj = 0; jj < 16; ++jj)
                *(double2*)&rowb[32 + 2 * jj] = double2{A[2 * jj], A[2 * jj + 1]};
        }
        // same-wave LDS ordering (lgkmcnt) makes the dump visible

        double x  = rowb[t];
        double x1 = rowb[k + 1];
        double xm = (t > k) ? x : 0.0;
        double sigma = dpp_sum64(xm * xm);

        double alpha = 0.0, u = 0.0, w = 0.0, rK = 0.0;
        bool run = (sigma > 1e-300);
        if (run) {
            double sq = sqrt(sigma);
            alpha = (x1 >= 0.0) ? -sq : sq;
            rK = 1.0 / (sigma - x1 * alpha);
            u = (t == k + 1) ? (x - alpha) : xm;
        }
        ubuf[t] = u;
        if (t == 0) { dbuf[k] = rowb[k]; ebuf[k] = alpha; }

        if (run) {
            double p0 = 0.0, p1 = 0.0;
            #pragma unroll
            for (int jj = 0; jj < 16; ++jj) {
                double2 uv = *(const double2*)&ubuf[32 + 2 * jj];
                p0 += A[2 * jj]     * uv.x;
                p1 += A[2 * jj + 1] * uv.y;
            }
            double p = (t > k) ? (p0 + p1) * rK : 0.0;
            double cc = dpp_sum64(u * p) * (0.5 * rK);
            w = p - cc * u;
        }
        wbuf[t] = w;

        if (run) {
            #pragma unroll
            for (int jj = 0; jj < 16; ++jj) {
                double2 uv = *(const double2*)&ubuf[32 + 2 * jj];
                double2 wv = *(const double2*)&wbuf[32 + 2 * jj];
                A[2 * jj]     -= u * wv.x + w * uv.x;
                A[2 * jj + 1] -= u * wv.y + w * uv.y;
            }
        }
    }

    if (t == 62) dbuf[62] = A[30];                     // (62,62)
    if (t == 63) { dbuf[63] = A[31];                   // (63,63)
                   ebuf[62] = A[30]; }                 // (63,62)
    if (t == 0)  ebuf[63] = 0.0;
    // same-wave ordering; dbuf/ebuf phase-1 entries were barrier-ordered

    // ---- fused bisection: wave 1, pure VALU (readlane broadcasts) -------
    double dv = dbuf[t];                               // lane t: d_t
    double ev = ebuf[t];                               // lane t: e_t
    double e2v = ev * ev;
    double eav = fabs(ev);

    int tsrc = (t > 0) ? (t - 1) : 0;
    double el = __shfl(eav, tsrc, 64);
    el = (t > 0) ? el : 0.0;
    double er = (t < 63) ? eav : 0.0;
    double rad = el + er;
    double lo = wmin(dv - rad);
    double hi = wmax(dv + rad);
    double mid0 = 0.5 * (lo + hi);
    double half = (0.5 * (hi - lo) + 1e-12) * 1.0000001;
    double a = mid0 - half;
    double b = mid0 + half;

    double d0 = rdlaned(dv, 0);

    #pragma unroll 1
    for (int it = 0; it < 30; ++it) {
        double xm2 = 0.5 * (a + b);
        double pm = 1.0;
        double p  = d0 - xm2;
        int cnt = (p < 0.0);
        #pragma unroll
        for (int i = 1; i < 64; ++i) {
            double di  = rdlaned(dv, i);               // wave-uniform, VALU
            double e2i = rdlaned(e2v, i - 1);          // wave-uniform, VALU
            double pi = (di - xm2) * p - e2i * pm;
            cnt += ((pi < 0.0) != (p < 0.0));
            double ap = fabs(pi);
            double s = (ap > 1e150) ? 1e-150 : ((ap < 1e-150) ? 1e150 : 1.0);
            pm = p * s;
            p  = pi * s;
        }
        if (cnt > t) b = xm2; else a = xm2;
    }

    double lam = 0.5 * (a + b);
    double v = fmax(lam, 1e-8);
    out[(size_t)g * 64 + (63 - t)] = (float)log(v);
}

// ---------------------------------------------------------------------------
// Fallback GEMM (in-kernel split, full N=4096) — used only if ws too small.
// ---------------------------------------------------------------------------
__global__ __launch_bounds__(256) void gemm_bt(const float* __restrict__ Xf,
                                               const float* __restrict__ Wf,
                                               const float* __restrict__ biasf,
                                               float* __restrict__ M)
{
    const int K = 2048, N = 4096;
    __shared__ unsigned short AsH[128][32];
    __shared__ unsigned short AsM[128][32];
    __shared__ unsigned short AsL[128][32];
    __shared__ unsigned short BsH[128][32];
    __shared__ unsigned short BsM[128][32];
    __shared__ unsigned short BsL[128][32];

    int tid  = threadIdx.x;
    int m0   = blockIdx.y * 128;
    int n0   = blockIdx.x * 128;
    int wid  = tid >> 6;
    int lane = tid & 63;
    int wm   = (wid >> 1) * 64;
    int wn   = (wid & 1) * 64;
    int l16  = lane & 15;
    int quad = lane >> 4;

    f32x4 acc[4][4];
    #pragma unroll
    for (int mi = 0; mi < 4; ++mi)
        #pragma unroll
        for (int ni = 0; ni < 4; ++ni)
            acc[mi][ni] = f32x4{0.f, 0.f, 0.f, 0.f};

    for (int k0 = 0; k0 < K; k0 += 32) {
        #pragma unroll
        for (int s = 0; s < 4; ++s) {
            int c  = tid + s * 256;
            int r  = c >> 3;
            int kc = (c & 7) << 2;
            {
                float4 v = *(const float4*)&Xf[(size_t)(m0 + r) * K + k0 + kc];
                ushort4 h, mm_, l; float r1;
                h.x = f32_to_bf16_rn(v.x); r1 = v.x - bf16f(h.x);
                mm_.x = f32_to_bf16_rn(r1); l.x = f32_to_bf16_rn(r1 - bf16f(mm_.x));
                h.y = f32_to_bf16_rn(v.y); r1 = v.y - bf16f(h.y);
                mm_.y = f32_to_bf16_rn(r1); l.y = f32_to_bf16_rn(r1 - bf16f(mm_.y));
                h.z = f32_to_bf16_rn(v.z); r1 = v.z - bf16f(h.z);
                mm_.z = f32_to_bf16_rn(r1); l.z = f32_to_bf16_rn(r1 - bf16f(mm_.z));
                h.w = f32_to_bf16_rn(v.w); r1 = v.w - bf16f(h.w);
                mm_.w = f32_to_bf16_rn(r1); l.w = f32_to_bf16_rn(r1 - bf16f(mm_.w));
                *(ushort4*)&AsH[r][kc] = h; *(ushort4*)&AsM[r][kc] = mm_; *(ushort4*)&AsL[r][kc] = l;
            }
            {
                float4 v = *(const float4*)&Wf[(size_t)(n0 + r) * K + k0 + kc];
                ushort4 h, mm_, l; float r1;
                h.x = f32_to_bf16_rn(v.x); r1 = v.x - bf16f(h.x);
                mm_.x = f32_to_bf16_rn(r1); l.x = f32_to_bf16_rn(r1 - bf16f(mm_.x));
                h.y = f32_to_bf16_rn(v.y); r1 = v.y - bf16f(h.y);
                mm_.y = f32_to_bf16_rn(r1); l.y = f32_to_bf16_rn(r1 - bf16f(mm_.y));
                h.z = f32_to_bf16_rn(v.z); r1 = v.z - bf16f(h.z);
                mm_.z = f32_to_bf16_rn(r1); l.z = f32_to_bf16_rn(r1 - bf16f(mm_.z));
                h.w = f32_to_bf16_rn(v.w); r1 = v.w - bf16f(h.w);
                mm_.w = f32_to_bf16_rn(r1); l.w = f32_to_bf16_rn(r1 - bf16f(mm_.w));
                *(ushort4*)&BsH[r][kc] = h; *(ushort4*)&BsM[r][kc] = mm_; *(ushort4*)&BsL[r][kc] = l;
            }
        }
        __syncthreads();

        U8 ah[4], am[4], al[4], bh[4], bm[4], bl[4];
        #pragma unroll
        for (int mi = 0; mi < 4; ++mi) {
            ah[mi].u = *(const uint4*)&AsH[wm + mi * 16 + l16][quad * 8];
            am[mi].u = *(const uint4*)&AsM[wm + mi * 16 + l16][quad * 8];
            al[mi].u = *(const uint4*)&AsL[wm + mi * 16 + l16][quad * 8];
        }
        #pragma unroll
        for (int ni = 0; ni < 4; ++ni) {
            bh[ni].u = *(const uint4*)&BsH[wn + ni * 16 + l16][quad * 8];
            bm[ni].u = *(const uint4*)&BsM[wn + ni * 16 + l16][quad * 8];
            bl[ni].u = *(const uint4*)&BsL[wn + ni * 16 + l16][quad * 8];
        }

        #pragma unroll
        for (int mi = 0; mi < 4; ++mi)
            #pragma unroll
            for (int ni = 0; ni < 4; ++ni) {
                acc[mi][ni] = __builtin_amdgcn_mfma_f32_16x16x32_bf16(al[mi].b, bh[ni].b, acc[mi][ni], 0, 0, 0);
                acc[mi][ni] = __builtin_amdgcn_mfma_f32_16x16x32_bf16(ah[mi].b, bl[ni].b, acc[mi][ni], 0, 0, 0);
                acc[mi][ni] = __builtin_amdgcn_mfma_f32_16x16x32_bf16(am[mi].b, bm[ni].b, acc[mi][ni], 0, 0, 0);
                acc[mi][ni] = __builtin_amdgcn_mfma_f32_16x16x32_bf16(am[mi].b, bh[ni].b, acc[mi][ni], 0, 0, 0);
                acc[mi][ni] = __builtin_amdgcn_mfma_f32_16x16x32_bf16(ah[mi].b, bm[ni].b, acc[mi][ni], 0, 0, 0);
                acc[mi][ni] = __builtin_amdgcn_mfma_f32_16x16x32_bf16(ah[mi].b, bh[ni].b, acc[mi][ni], 0, 0, 0);
            }
        __syncthreads();
    }

    #pragma unroll
    for (int ni = 0; ni < 4; ++ni) {
        int col = n0 + wn + ni * 16 + l16;
        float bv = biasf[col];
        #pragma unroll
        for (int mi = 0; mi < 4; ++mi) {
            int row = m0 + wm + mi * 16 + quad * 4;
            #pragma unroll
            for (int r = 0; r < 4; ++r)
                M[(size_t)(row + r) * N + col] = acc[mi][ni][r] + bv;
        }
    }
}

// ---------------------------------------------------------------------------
// Fallback tridiag: full-M input with in-kernel symmetrization (old version).
// ---------------------------------------------------------------------------
__global__ __launch_bounds__(64, 2) void tridiag_full(const float* __restrict__ M,
                                                      const float* __restrict__ regf,
                                                      double* __restrict__ trid)
{
    __shared__ float Ms[64][65];
    __shared__ __align__(16) double rowb[64];
    __shared__ __align__(16) double ubuf[64];
    __shared__ __align__(16) double wbuf[64];
    __shared__ double dbuf[64];
    __shared__ double ebuf[64];

    int g = blockIdx.x;
    int t = threadIdx.x;
    const float* Mg = M + (size_t)g * 4096;

    for (int r = 0; r < 64; ++r)
        Ms[r][t] = Mg[r * 64 + t];
    __syncthreads();

    double regv = (double)regf[0];
    double A[64];
    #pragma unroll
    for (int j = 0; j < 64; ++j)
        A[j] = 0.5 * ((double)Ms[t][j] + (double)Ms[j][t]);
    #pragma unroll
    for (int j = 0; j < 64; ++j)
        A[j] += (j == t) ? regv : 0.0;

    #pragma unroll 1
    for (int k = 0; k < 62; ++k) {
        if (t == k) {
            #pragma unroll
            for (int j = 0; j < 32; ++j)
                *(double2*)&rowb[2 * j] = double2{A[2 * j], A[2 * j + 1]};
        }
        __syncthreads();

        double s0 = 0.0, s1 = 0.0;
        #pragma unroll
        for (int j = 0; j < 64; ++j) {
            double aj = (j > k) ? A[j] : 0.0;
            if (j & 1) s1 += aj * aj; else s0 += aj * aj;
        }
        double sigma = __shfl(s0 + s1, k, 64);
        double x  = rowb[t];
        double x1 = __shfl(x, k + 1, 64);

        double alpha = 0.0, u = 0.0, w = 0.0, Kh = 1.0;
        bool run = (sigma > 1e-300);
        if (run) {
            double sq = sqrt(sigma);
            alpha = (x1 >= 0.0) ? -sq : sq;
            Kh = sigma - x1 * alpha;
            u = (t == k + 1) ? (x - alpha) : ((t > k) ? x : 0.0);
        }
        ubuf[t] = u;
        if (t == 0) { dbuf[k] = rowb[k]; ebuf[k] = alpha; }
        __syncthreads();

        if (run) {
            double p0 = 0.0, p1 = 0.0;
            #pragma unroll
            for (int j = 0; j < 32; ++j) {
                double2 uv = *(const double2*)&ubuf[2 * j];
                p0 += A[2 * j]     * uv.x;
                p1 += A[2 * j + 1] * uv.y;
            }
            double p = (t > k) ? (p0 + p1) / Kh : 0.0;
            double cc = wsum(u * p) / (2.0 * Kh);
            w = p - cc * u;
        }
        wbuf[t] = w;
        __syncthreads();

        if (run) {
            #pragma unroll
            for (int j = 0; j < 32; ++j) {
                double2 uv = *(const double2*)&ubuf[2 * j];
                double2 wv = *(const double2*)&wbuf[2 * j];
                A[2 * j]     -= u * wv.x + w * uv.x;
                A[2 * j + 1] -= u * wv.y + w * uv.y;
            }
        }
        __syncthreads();
    }

    if (t == 62) dbuf[62] = A[62];
    if (t == 63) { dbuf[63] = A[63]; ebuf[62] = A[62]; }
    if (t == 0)  ebuf[63] = 0.0;
    __syncthreads();

    double* tg = trid + (size_t)g * 128;
    tg[t]      = dbuf[t];
    tg[64 + t] = ebuf[t];
}

// ---------------------------------------------------------------------------
// Fallback bisection kernel (used only with the fallback path).
// ---------------------------------------------------------------------------
__global__ __launch_bounds__(64) void bisect_kernel(const double* __restrict__ trid,
                                                    float* __restrict__ out)
{
    __shared__ double dd[64];
    __shared__ double e2[64];
    __shared__ double ea[64];

    int g = blockIdx.x;
    int t = threadIdx.x;
    const double* tg = trid + (size_t)g * 128;

    double dv = tg[t];
    double ev = tg[64 + t];
    dd[t] = dv;
    ea[t] = fabs(ev);
    e2[t] = ev * ev;
    __syncthreads();

    double el  = (t > 0) ? ea[t - 1] : 0.0;
    double er  = (t < 63) ? ea[t] : 0.0;
    double rad = el + er;
    double lo = wmin(dv - rad);
    double hi = wmax(dv + rad);
    double mid0 = 0.5 * (lo + hi);
    double half = (0.5 * (hi - lo) + 1e-12) * 1.0000001;
    double a = mid0 - half;
    double b = mid0 + half;

    for (int it = 0; it < 30; ++it) {
        double xm = 0.5 * (a + b);
        double pm = 1.0;
        double p  = dd[0] - xm;
        int cnt = (p < 0.0);
        #pragma unroll
        for (int i = 1; i < 64; ++i) {
            double pi = (dd[i] - xm) * p - e2[i - 1] * pm;
            cnt += ((pi < 0.0) != (p < 0.0));
            double ap = fabs(pi);
            double s = (ap > 1e150) ? 1e-150 : ((ap < 1e-150) ? 1e150 : 1.0);
            pm = p * s;
            p  = pi * s;
        }
        if (cnt > t) b = xm; else a = xm;
    }

    double lam = 0.5 * (a + b);
    double v = fmax(lam, 1e-8);
    out[(size_t)g * 64 + (63 - t)] = (float)log(v);
}

// ---------------------------------------------------------------------------
extern "C" void kernel_launch(void* const* d_in, const int* in_sizes, int n_in,
                              void* d_out, int out_size, void* d_ws, size_t ws_size,
                              hipStream_t stream)
{
    const float* X    = (const float*)d_in[0]; // [2048,2048] fp32
    const float* Wt   = (const float*)d_in[1]; // [4096,2048] fp32
    const float* bias = (const float*)d_in[2]; // [4096] fp32
    const float* regp = (const float*)d_in[3]; // [1] fp32

    char* w = (char*)d_ws;
    float* out = (float*)d_out;                          // [2048,64] fp32

    const size_t NEED_FAST = 87826688ull;
    if (ws_size >= NEED_FAST) {
        float*  Mp   = (float*)w;                        // 2x 2048x2112 fp32 (split-K halves)
        unsigned short* Xh = (unsigned short*)(w + 36700160);
        unsigned short* Xm = (unsigned short*)(w + 45088768);
        unsigned short* Xl = (unsigned short*)(w + 53477376);
        unsigned short* Sh = (unsigned short*)(w + 61865984);
        unsigned short* Sm = (unsigned short*)(w + 70516736);
        unsigned short* Sl = (unsigned short*)(w + 79167488);
        float* bsym = (float*)(w + 87818240);            // 2112 fp32
        split2<<<dim3(8320), dim3(256), 0, stream>>>(X, Wt, bias, regp,
                                                     Xh, Xm, Xl, Sh, Sm, Sl, bsym);
        gemm_packed<<<dim3(1056), dim3(256), 0, stream>>>(Xh, Xm, Xl, Sh, Sm, Sl, bsym, Mp);
        tridiag_bisect<<<dim3(2048), dim3(128), 0, stream>>>(Mp, out);
    } else {
        float*  M    = (float*)w;                        // 32 MB
        double* trid = (double*)(w + 33554432);          // 2 MB
        gemm_bt<<<dim3(32, 16), dim3(256), 0, stream>>>(X, Wt, bias, M);
        tridiag_full<<<dim3(2048), dim3(64), 0, stream>>>(M, regp, trid);
        bisect_kernel<<<dim3(2048), dim3(64), 0, stream>>>(trid, out);
    }
}

// Round 6
// 501.362 us; speedup vs baseline: 1.1456x; 1.1456x over previous
//
#include <hip/hip_runtime.h>

typedef __bf16 bf16x8 __attribute__((ext_vector_type(8)));
typedef float f32x4 __attribute__((ext_vector_type(4)));

union U8 { uint4 u; bf16x8 b; };

__device__ inline float bf16f(unsigned short h) {
    return __uint_as_float(((unsigned)h) << 16);
}

__device__ inline unsigned short f32_to_bf16_rn(float f) {
    unsigned u = __float_as_uint(f);
    unsigned rounding = 0x7FFFu + ((u >> 16) & 1u);
    u += rounding;
    return (unsigned short)(u >> 16);
}

__device__ inline double wsum(double v) {
    #pragma unroll
    for (int m = 32; m; m >>= 1) v += __shfl_xor(v, m, 64);
    return v;
}
__device__ inline double wmin(double v) {
    #pragma unroll
    for (int m = 32; m; m >>= 1) v = fmin(v, __shfl_xor(v, m, 64));
    return v;
}
__device__ inline double wmax(double v) {
    #pragma unroll
    for (int m = 32; m; m >>= 1) v = fmax(v, __shfl_xor(v, m, 64));
    return v;
}

// ---------------------------------------------------------------------------
// Full-wave (64-lane) fp64 sum on the VALU pipe only (DPP butterflies +
// row broadcasts), result broadcast to all lanes via readlane.
// Validated on-device in rounds 3/4 (bit-identical absmax).
// ---------------------------------------------------------------------------
__device__ inline double dpp_sum64(double v) {
    union DU { double d; int i[2]; };
    DU x, t; x.d = v;
    t.i[0] = __builtin_amdgcn_update_dpp(0, x.i[0], 0xB1, 0xF, 0xF, true);
    t.i[1] = __builtin_amdgcn_update_dpp(0, x.i[1], 0xB1, 0xF, 0xF, true);
    x.d += t.d;
    t.i[0] = __builtin_amdgcn_update_dpp(0, x.i[0], 0x4E, 0xF, 0xF, true);
    t.i[1] = __builtin_amdgcn_update_dpp(0, x.i[1], 0x4E, 0xF, 0xF, true);
    x.d += t.d;
    t.i[0] = __builtin_amdgcn_update_dpp(0, x.i[0], 0x141, 0xF, 0xF, true);
    t.i[1] = __builtin_amdgcn_update_dpp(0, x.i[1], 0x141, 0xF, 0xF, true);
    x.d += t.d;
    t.i[0] = __builtin_amdgcn_update_dpp(0, x.i[0], 0x140, 0xF, 0xF, true);
    t.i[1] = __builtin_amdgcn_update_dpp(0, x.i[1], 0x140, 0xF, 0xF, true);
    x.d += t.d;
    t.i[0] = __builtin_amdgcn_update_dpp(0, x.i[0], 0x142, 0xF, 0xF, true);
    t.i[1] = __builtin_amdgcn_update_dpp(0, x.i[1], 0x142, 0xF, 0xF, true);
    x.d += t.d;
    t.i[0] = __builtin_amdgcn_update_dpp(0, x.i[0], 0x143, 0xF, 0xF, true);
    t.i[1] = __builtin_amdgcn_update_dpp(0, x.i[1], 0x143, 0xF, 0xF, true);
    x.d += t.d;
    int lo = __builtin_amdgcn_readlane(x.i[0], 63);
    int hi = __builtin_amdgcn_readlane(x.i[1], 63);
    return __hiloint2double(hi, lo);
}

__device__ inline float4 f4add(float4 a, float4 b) {
    return float4{a.x + b.x, a.y + b.y, a.z + b.z, a.w + b.w};
}

#define AS1C(p) ((const __attribute__((address_space(1))) void*)(p))
#define AS3(p)  ((__attribute__((address_space(3))) void*)(p))

// ---------------------------------------------------------------------------
// Kernel 0: split X into 3 bf16 planes; build PACKED-SYMMETRIC W planes
// (upper triangle incl. diagonal, row-major by i: 2080 real rows + 32 pad)
// and symmetric bias (reg folded into diagonal).
// packed p -> (i,j), i<=j ; start(i) = i*(129-i)/2.
// ---------------------------------------------------------------------------
__global__ __launch_bounds__(256) void split2(
    const float* __restrict__ X, const float* __restrict__ W,
    const float* __restrict__ b, const float* __restrict__ regp,
    unsigned short* __restrict__ Xh, unsigned short* __restrict__ Xm, unsigned short* __restrict__ Xl,
    unsigned short* __restrict__ Sh, unsigned short* __restrict__ Sm, unsigned short* __restrict__ Sl,
    float* __restrict__ bsym)
{
    size_t i4 = (size_t)blockIdx.x * 256 + threadIdx.x;   // total 2129920 float4 items

    if (i4 < 1048576) {                                    // X part: 2048x2048 / 4
        float4 v = ((const float4*)X)[i4];
        ushort4 h, m, l; float r1;
        h.x = f32_to_bf16_rn(v.x); r1 = v.x - bf16f(h.x);
        m.x = f32_to_bf16_rn(r1);  l.x = f32_to_bf16_rn(r1 - bf16f(m.x));
        h.y = f32_to_bf16_rn(v.y); r1 = v.y - bf16f(h.y);
        m.y = f32_to_bf16_rn(r1);  l.y = f32_to_bf16_rn(r1 - bf16f(m.y));
        h.z = f32_to_bf16_rn(v.z); r1 = v.z - bf16f(h.z);
        m.z = f32_to_bf16_rn(r1);  l.z = f32_to_bf16_rn(r1 - bf16f(m.z));
        h.w = f32_to_bf16_rn(v.w); r1 = v.w - bf16f(h.w);
        m.w = f32_to_bf16_rn(r1);  l.w = f32_to_bf16_rn(r1 - bf16f(m.w));
        ((ushort4*)Xh)[i4] = h;
        ((ushort4*)Xm)[i4] = m;
        ((ushort4*)Xl)[i4] = l;
        return;
    }

    size_t q = i4 - 1048576;                               // 2112 rows x 512 float4
    int p  = (int)(q >> 9);
    int d4 = (int)(q & 511);

    if (p >= 2080) {                                       // pad rows: zeros
        ushort4 z; z.x = 0; z.y = 0; z.z = 0; z.w = 0;
        ((ushort4*)Sh)[q] = z; ((ushort4*)Sm)[q] = z; ((ushort4*)Sl)[q] = z;
        if (d4 == 0) bsym[p] = 0.0f;
        return;
    }

    // invert packed index: i = floor((129 - sqrt(129^2 - 8p))/2), then fixup
    double sd = sqrt(16641.0 - 8.0 * (double)p);
    int i = (int)((129.0 - sd) * 0.5);
    if (i < 0) i = 0;
    if (i > 63) i = 63;
    while (i < 63 && ((i + 1) * (128 - i)) / 2 <= p) ++i;
    while (i > 0 && (i * (129 - i)) / 2 > p) --i;
    int j = i + (p - (i * (129 - i)) / 2);
    int e1 = i * 64 + j;
    int e2 = j * 64 + i;

    float4 v1 = ((const float4*)W)[(size_t)e1 * 512 + d4];
    float4 v2 = ((const float4*)W)[(size_t)e2 * 512 + d4];
    float4 v;
    v.x = 0.5f * (v1.x + v2.x);
    v.y = 0.5f * (v1.y + v2.y);
    v.z = 0.5f * (v1.z + v2.z);
    v.w = 0.5f * (v1.w + v2.w);

    ushort4 h, m, l; float r1;
    h.x = f32_to_bf16_rn(v.x); r1 = v.x - bf16f(h.x);
    m.x = f32_to_bf16_rn(r1);  l.x = f32_to_bf16_rn(r1 - bf16f(m.x));
    h.y = f32_to_bf16_rn(v.y); r1 = v.y - bf16f(h.y);
    m.y = f32_to_bf16_rn(r1);  l.y = f32_to_bf16_rn(r1 - bf16f(m.y));
    h.z = f32_to_bf16_rn(v.z); r1 = v.z - bf16f(h.z);
    m.z = f32_to_bf16_rn(r1);  l.z = f32_to_bf16_rn(r1 - bf16f(m.z));
    h.w = f32_to_bf16_rn(v.w); r1 = v.w - bf16f(h.w);
    m.w = f32_to_bf16_rn(r1);  l.w = f32_to_bf16_rn(r1 - bf16f(m.w));
    ((ushort4*)Sh)[q] = h;
    ((ushort4*)Sm)[q] = m;
    ((ushort4*)Sl)[q] = l;

    if (d4 == 0)
        bsym[p] = 0.5f * (b[e1] + b[e2]) + ((i == j) ? regp[0] : 0.0f);
}

// ---------------------------------------------------------------------------
// Kernel 1: 6-plane bf16 GEMM over PACKED columns, SPLIT-K x2.
// 1056 blocks (= 8 XCD x 132), each does half of K into its own Mp half.
// 128x64 tiles, 36 KB LDS, bijective XCD swizzle per K-half.
// ---------------------------------------------------------------------------
__global__ __launch_bounds__(256) void gemm_packed(
    const unsigned short* __restrict__ Xh, const unsigned short* __restrict__ Xm,
    const unsigned short* __restrict__ Xl,
    const unsigned short* __restrict__ Sh, const unsigned short* __restrict__ Sm,
    const unsigned short* __restrict__ Sl,
    const float* __restrict__ bsym, float* __restrict__ Mp)
{
    const int K = 2048, NP = 2112;
    __shared__ unsigned short S[18432];   // 36 KB

    int tid  = threadIdx.x;
    int id   = blockIdx.x;                 // 0..1055
    int c    = id & 7;                     // XCD (hw round-robins id%8)
    int sid  = id >> 3;                    // 0..131
    int kh   = (sid >= 66) ? 1 : 0;        // K-half
    int sidh = sid - kh * 66;              // 0..65
    int wg   = c * 66 + sidh;              // bijective within each K-half
    int bx   = wg % 33;                    // 0..32 packed-col tile
    int by   = wg / 33;                    // 0..15
    int m0   = by * 128;
    int n0   = bx * 64;
    int kb   = kh * 1024;

    int wave = tid >> 6;
    int lane = tid & 63;
    int l16  = lane & 15;
    int quad = lane >> 4;
    int wm   = wave * 32;

    const unsigned short* gpA[3];
    const unsigned short* gpB[3];
    gpA[0] = Xh + (size_t)m0 * K;
    gpA[1] = Xm + (size_t)m0 * K;
    gpA[2] = Xl + (size_t)m0 * K;
    gpB[0] = Sh + (size_t)n0 * K;
    gpB[1] = Sm + (size_t)n0 * K;
    gpB[2] = Sl + (size_t)n0 * K;

    int rA = lane >> 2;              // 0..15
    int cA = (lane & 3) << 3;        // ushort col offset 0,8,16,24

    f32x4 acc[2][4];
    #pragma unroll
    for (int mi = 0; mi < 2; ++mi)
        #pragma unroll
        for (int ni = 0; ni < 4; ++ni)
            acc[mi][ni] = f32x4{0.f, 0.f, 0.f, 0.f};

    for (int k0 = kb; k0 < kb + 1024; k0 += 32) {
        __syncthreads();
        #pragma unroll
        for (int p = 0; p < 3; ++p) {
            #pragma unroll
            for (int q = 0; q < 2; ++q) {
                const unsigned short* g = gpA[p] + (size_t)(32 * wave + 16 * q + rA) * K + k0 + cA;
                char* l = (char*)S + p * 8192 + wave * 2048 + q * 1024;
                __builtin_amdgcn_global_load_lds(AS1C(g), AS3(l), 16, 0, 0);
            }
            {
                const unsigned short* g = gpB[p] + (size_t)(16 * wave + rA) * K + k0 + cA;
                char* l = (char*)S + 24576 + p * 4096 + wave * 1024;
                __builtin_amdgcn_global_load_lds(AS1C(g), AS3(l), 16, 0, 0);
            }
        }
        __syncthreads();

        U8 ah[2], am[2], al[2], bh[4], bm[4], bl[4];
        #pragma unroll
        for (int mi = 0; mi < 2; ++mi) {
            int ro = (wm + mi * 16 + l16) * 32 + quad * 8;
            ah[mi].u = *(const uint4*)&S[ro];
            am[mi].u = *(const uint4*)&S[4096 + ro];
            al[mi].u = *(const uint4*)&S[8192 + ro];
        }
        #pragma unroll
        for (int ni = 0; ni < 4; ++ni) {
            int ro = (ni * 16 + l16) * 32 + quad * 8;
            bh[ni].u = *(const uint4*)&S[12288 + ro];
            bm[ni].u = *(const uint4*)&S[14336 + ro];
            bl[ni].u = *(const uint4*)&S[16384 + ro];
        }

        #pragma unroll
        for (int mi = 0; mi < 2; ++mi)
            #pragma unroll
            for (int ni = 0; ni < 4; ++ni) {
                acc[mi][ni] = __builtin_amdgcn_mfma_f32_16x16x32_bf16(
                    al[mi].b, bh[ni].b, acc[mi][ni], 0, 0, 0);
                acc[mi][ni] = __builtin_amdgcn_mfma_f32_16x16x32_bf16(
                    ah[mi].b, bl[ni].b, acc[mi][ni], 0, 0, 0);
                acc[mi][ni] = __builtin_amdgcn_mfma_f32_16x16x32_bf16(
                    am[mi].b, bm[ni].b, acc[mi][ni], 0, 0, 0);
                acc[mi][ni] = __builtin_amdgcn_mfma_f32_16x16x32_bf16(
                    am[mi].b, bh[ni].b, acc[mi][ni], 0, 0, 0);
                acc[mi][ni] = __builtin_amdgcn_mfma_f32_16x16x32_bf16(
                    ah[mi].b, bm[ni].b, acc[mi][ni], 0, 0, 0);
                acc[mi][ni] = __builtin_amdgcn_mfma_f32_16x16x32_bf16(
                    ah[mi].b, bh[ni].b, acc[mi][ni], 0, 0, 0);
            }
    }

    float* Mout = Mp + (size_t)kh * 4325376;   // 2048*2112 floats per half
    #pragma unroll
    for (int ni = 0; ni < 4; ++ni) {
        int col = n0 + ni * 16 + l16;
        float bv = kh ? 0.0f : bsym[col];
        #pragma unroll
        for (int mi = 0; mi < 2; ++mi) {
            int row = m0 + wm + mi * 16 + quad * 4;
            #pragma unroll
            for (int r = 0; r < 4; ++r)
                Mout[(size_t)(row + r) * NP + col] = acc[mi][ni][r] + bv;
        }
    }
}

// ---------------------------------------------------------------------------
// Kernel 2 (v4, proven 214 us): fp64 Householder tridiag, 2-wave column-split.
//  - dpp reductions on VALU pipe; barrier-free phase 2 (wave 1 only).
// ---------------------------------------------------------------------------
__global__ __launch_bounds__(128, 4) void tridiag_packed4(
    const float* __restrict__ Mp, double* __restrict__ trid)
{
    __shared__ __align__(16) float Ls[2112];           // packed row (8.25 KB)
    __shared__ __align__(16) double rowb[64];          // row k (= col k) dump
    __shared__ __align__(16) double ubuf[64];
    __shared__ __align__(16) double wbuf[64];
    __shared__ __align__(16) double pps[128];          // p partials per wave
    __shared__ double dbuf[64];
    __shared__ double ebuf[64];

    int g   = blockIdx.x;
    int tid = threadIdx.x;
    int h   = tid >> 6;                                // wave 0/1
    int t   = tid & 63;                                // row index
    int base = 32 * h;                                 // first owned column

    const float4* Pg0 = (const float4*)(Mp + (size_t)g * 2112);
    const float4* Pg1 = (const float4*)(Mp + 4325376 + (size_t)g * 2112);
    float4* L4 = (float4*)Ls;
    #pragma unroll
    for (int s = 0; s < 4; ++s)
        L4[s * 128 + tid] = f4add(Pg0[s * 128 + tid], Pg1[s * 128 + tid]);
    if (tid < 16) L4[512 + tid] = f4add(Pg0[512 + tid], Pg1[512 + tid]);
    __syncthreads();

    // lane (h,t): row t, columns base..base+31 from packed upper triangle
    double A[32];
    #pragma unroll
    for (int jj = 0; jj < 32; ++jj) {
        int cj = base + jj;
        int lo = (t < cj) ? t : cj;
        int hi = t + cj - lo;
        int idx = ((lo * (129 - lo)) >> 1) + (hi - lo);
        A[jj] = (double)Ls[idx];
    }

    // ---- phase 1: k = 0..31, both waves active, 4 barriers/iter ---------
    #pragma unroll 1
    for (int k = 0; k < 32; ++k) {
        if (t == k) {                                  // dump own half of row k
            #pragma unroll
            for (int jj = 0; jj < 16; ++jj)
                *(double2*)&rowb[base + 2 * jj] = double2{A[2 * jj], A[2 * jj + 1]};
        }
        __syncthreads();                               // B1

        double x  = rowb[t];
        double x1 = rowb[k + 1];
        double xm = (t > k) ? x : 0.0;
        double sigma = dpp_sum64(xm * xm);             // VALU-pipe reduction

        double alpha = 0.0, u = 0.0, w = 0.0, rK = 0.0;
        bool run = (sigma > 1e-300);                   // uniform
        if (run) {
            double sq = sqrt(sigma);
            alpha = (x1 >= 0.0) ? -sq : sq;
            rK = 1.0 / (sigma - x1 * alpha);
            u = (t == k + 1) ? (x - alpha) : xm;
        }
        if (h == 0) ubuf[t] = u;
        if (tid == 0) { dbuf[k] = rowb[k]; ebuf[k] = alpha; }
        __syncthreads();                               // B2

        double ph = 0.0;
        if (run) {
            double p0 = 0.0, p1 = 0.0;
            #pragma unroll
            for (int jj = 0; jj < 16; ++jj) {
                double2 uv = *(const double2*)&ubuf[base + 2 * jj];
                p0 += A[2 * jj]     * uv.x;
                p1 += A[2 * jj + 1] * uv.y;
            }
            ph = p0 + p1;
        }
        pps[h * 64 + t] = ph;
        __syncthreads();                               // B3

        if (run) {
            double p = (t > k) ? (pps[t] + pps[64 + t]) * rK : 0.0;
            double cc = dpp_sum64(u * p) * (0.5 * rK); // VALU-pipe reduction
            w = p - cc * u;
        }
        if (h == 0) wbuf[t] = w;
        __syncthreads();                               // B4

        if (run) {
            #pragma unroll
            for (int jj = 0; jj < 16; ++jj) {
                double2 uv = *(const double2*)&ubuf[base + 2 * jj];
                double2 wv = *(const double2*)&wbuf[base + 2 * jj];
                A[2 * jj]     -= u * wv.x + w * uv.x;
                A[2 * jj + 1] -= u * wv.y + w * uv.y;
            }
        }
    }

    // wave 0's columns are frozen from here; it exits. No further barriers.
    if (h == 0) return;

    // ---- phase 2: k = 32..61, wave 1 only, barrier-free -----------------
    #pragma unroll 1
    for (int k = 32; k < 62; ++k) {
        if (t == k) {
            #pragma unroll
            for (int jj = 0; jj < 16; ++jj)
                *(double2*)&rowb[32 + 2 * jj] = double2{A[2 * jj], A[2 * jj + 1]};
        }
        // same-wave LDS ordering (lgkmcnt) makes the dump visible

        double x  = rowb[t];
        double x1 = rowb[k + 1];
        double xm = (t > k) ? x : 0.0;
        double sigma = dpp_sum64(xm * xm);

        double alpha = 0.0, u = 0.0, w = 0.0, rK = 0.0;
        bool run = (sigma > 1e-300);
        if (run) {
            double sq = sqrt(sigma);
            alpha = (x1 >= 0.0) ? -sq : sq;
            rK = 1.0 / (sigma - x1 * alpha);
            u = (t == k + 1) ? (x - alpha) : xm;
        }
        ubuf[t] = u;
        if (t == 0) { dbuf[k] = rowb[k]; ebuf[k] = alpha; }

        if (run) {
            double p0 = 0.0, p1 = 0.0;
            #pragma unroll
            for (int jj = 0; jj < 16; ++jj) {
                double2 uv = *(const double2*)&ubuf[32 + 2 * jj];
                p0 += A[2 * jj]     * uv.x;
                p1 += A[2 * jj + 1] * uv.y;
            }
            double p = (t > k) ? (p0 + p1) * rK : 0.0;
            double cc = dpp_sum64(u * p) * (0.5 * rK);
            w = p - cc * u;
        }
        wbuf[t] = w;

        if (run) {
            #pragma unroll
            for (int jj = 0; jj < 16; ++jj) {
                double2 uv = *(const double2*)&ubuf[32 + 2 * jj];
                double2 wv = *(const double2*)&wbuf[32 + 2 * jj];
                A[2 * jj]     -= u * wv.x + w * uv.x;
                A[2 * jj + 1] -= u * wv.y + w * uv.y;
            }
        }
    }

    if (t == 62) dbuf[62] = A[30];                     // (62,62)
    if (t == 63) { dbuf[63] = A[31];                   // (63,63)
                   ebuf[62] = A[30]; }                 // (63,62)
    if (t == 0)  ebuf[63] = 0.0;
    // same-wave ordering; dbuf/ebuf phase-1 entries were barrier-ordered

    double* tg = trid + (size_t)g * 128;
    tg[t]      = dbuf[t];
    tg[64 + t] = ebuf[t];
}

// ---------------------------------------------------------------------------
// Kernel 3 (v2): Sturm bisection, VALU-lean inner loop.
// Rescale only every 4 steps (thresholds 1e120): amortized ~6.25 VALU ops
// per Sturm step vs ~11 with per-step rescale. Sign counts are invariant
// under positive scaling; growth per step bounded by (|d-x|+e^2) ~ 1e3, so
// 4 unscaled steps keep |p| within [1e-132, 1e132] -- no over/underflow.
// ---------------------------------------------------------------------------
__global__ __launch_bounds__(64) void bisect_kernel(const double* __restrict__ trid,
                                                    float* __restrict__ out)
{
    __shared__ double dd[64];
    __shared__ double e2[64];
    __shared__ double ea[64];

    int g = blockIdx.x;
    int t = threadIdx.x;
    const double* tg = trid + (size_t)g * 128;

    double dv = tg[t];
    double ev = tg[64 + t];
    dd[t] = dv;
    ea[t] = fabs(ev);
    e2[t] = ev * ev;
    __syncthreads();

    double el  = (t > 0) ? ea[t - 1] : 0.0;
    double er  = (t < 63) ? ea[t] : 0.0;
    double rad = el + er;
    double lo = wmin(dv - rad);
    double hi = wmax(dv + rad);
    double mid0 = 0.5 * (lo + hi);
    double half = (0.5 * (hi - lo) + 1e-12) * 1.0000001;
    double a = mid0 - half;
    double b = mid0 + half;

    #pragma unroll 1
    for (int it = 0; it < 30; ++it) {
        double xm = 0.5 * (a + b);
        double pm = 1.0;
        double p  = dd[0] - xm;
        int cnt = (p < 0.0);
        #pragma unroll
        for (int i = 1; i < 64; ++i) {
            double pi = (dd[i] - xm) * p - e2[i - 1] * pm;
            cnt += ((pi < 0.0) != (p < 0.0));
            pm = p;
            p  = pi;
            if ((i & 3) == 0) {                        // rescale every 4 steps
                double ap = fabs(p);
                double s = (ap > 1e120) ? 1e-120 : ((ap < 1e-120) ? 1e120 : 1.0);
                pm *= s;
                p  *= s;
            }
        }
        if (cnt > t) b = xm; else a = xm;
    }

    double lam = 0.5 * (a + b);
    double v = fmax(lam, 1e-8);
    out[(size_t)g * 64 + (63 - t)] = (float)log(v);
}

// ---------------------------------------------------------------------------
// Fallback GEMM (in-kernel split, full N=4096) — used only if ws too small.
// ---------------------------------------------------------------------------
__global__ __launch_bounds__(256) void gemm_bt(const float* __restrict__ Xf,
                                               const float* __restrict__ Wf,
                                               const float* __restrict__ biasf,
                                               float* __restrict__ M)
{
    const int K = 2048, N = 4096;
    __shared__ unsigned short AsH[128][32];
    __shared__ unsigned short AsM[128][32];
    __shared__ unsigned short AsL[128][32];
    __shared__ unsigned short BsH[128][32];
    __shared__ unsigned short BsM[128][32];
    __shared__ unsigned short BsL[128][32];

    int tid  = threadIdx.x;
    int m0   = blockIdx.y * 128;
    int n0   = blockIdx.x * 128;
    int wid  = tid >> 6;
    int lane = tid & 63;
    int wm   = (wid >> 1) * 64;
    int wn   = (wid & 1) * 64;
    int l16  = lane & 15;
    int quad = lane >> 4;

    f32x4 acc[4][4];
    #pragma unroll
    for (int mi = 0; mi < 4; ++mi)
        #pragma unroll
        for (int ni = 0; ni < 4; ++ni)
            acc[mi][ni] = f32x4{0.f, 0.f, 0.f, 0.f};

    for (int k0 = 0; k0 < K; k0 += 32) {
        #pragma unroll
        for (int s = 0; s < 4; ++s) {
            int c  = tid + s * 256;
            int r  = c >> 3;
            int kc = (c & 7) << 2;
            {
                float4 v = *(const float4*)&Xf[(size_t)(m0 + r) * K + k0 + kc];
                ushort4 h, mm_, l; float r1;
                h.x = f32_to_bf16_rn(v.x); r1 = v.x - bf16f(h.x);
                mm_.x = f32_to_bf16_rn(r1); l.x = f32_to_bf16_rn(r1 - bf16f(mm_.x));
                h.y = f32_to_bf16_rn(v.y); r1 = v.y - bf16f(h.y);
                mm_.y = f32_to_bf16_rn(r1); l.y = f32_to_bf16_rn(r1 - bf16f(mm_.y));
                h.z = f32_to_bf16_rn(v.z); r1 = v.z - bf16f(h.z);
                mm_.z = f32_to_bf16_rn(r1); l.z = f32_to_bf16_rn(r1 - bf16f(mm_.z));
                h.w = f32_to_bf16_rn(v.w); r1 = v.w - bf16f(h.w);
                mm_.w = f32_to_bf16_rn(r1); l.w = f32_to_bf16_rn(r1 - bf16f(mm_.w));
                *(ushort4*)&AsH[r][kc] = h; *(ushort4*)&AsM[r][kc] = mm_; *(ushort4*)&AsL[r][kc] = l;
            }
            {
                float4 v = *(const float4*)&Wf[(size_t)(n0 + r) * K + k0 + kc];
                ushort4 h, mm_, l; float r1;
                h.x = f32_to_bf16_rn(v.x); r1 = v.x - bf16f(h.x);
                mm_.x = f32_to_bf16_rn(r1); l.x = f32_to_bf16_rn(r1 - bf16f(mm_.x));
                h.y = f32_to_bf16_rn(v.y); r1 = v.y - bf16f(h.y);
                mm_.y = f32_to_bf16_rn(r1); l.y = f32_to_bf16_rn(r1 - bf16f(mm_.y));
                h.z = f32_to_bf16_rn(v.z); r1 = v.z - bf16f(h.z);
                mm_.z = f32_to_bf16_rn(r1); l.z = f32_to_bf16_rn(r1 - bf16f(mm_.z));
                h.w = f32_to_bf16_rn(v.w); r1 = v.w - bf16f(h.w);
                mm_.w = f32_to_bf16_rn(r1); l.w = f32_to_bf16_rn(r1 - bf16f(mm_.w));
                *(ushort4*)&BsH[r][kc] = h; *(ushort4*)&BsM[r][kc] = mm_; *(ushort4*)&BsL[r][kc] = l;
            }
        }
        __syncthreads();

        U8 ah[4], am[4], al[4], bh[4], bm[4], bl[4];
        #pragma unroll
        for (int mi = 0; mi < 4; ++mi) {
            ah[mi].u = *(const uint4*)&AsH[wm + mi * 16 + l16][quad * 8];
            am[mi].u = *(const uint4*)&AsM[wm + mi * 16 + l16][quad * 8];
            al[mi].u = *(const uint4*)&AsL[wm + mi * 16 + l16][quad * 8];
        }
        #pragma unroll
        for (int ni = 0; ni < 4; ++ni) {
            bh[ni].u = *(const uint4*)&BsH[wn + ni * 16 + l16][quad * 8];
            bm[ni].u = *(const uint4*)&BsM[wn + ni * 16 + l16][quad * 8];
            bl[ni].u = *(const uint4*)&BsL[wn + ni * 16 + l16][quad * 8];
        }

        #pragma unroll
        for (int mi = 0; mi < 4; ++mi)
            #pragma unroll
            for (int ni = 0; ni < 4; ++ni) {
                acc[mi][ni] = __builtin_amdgcn_mfma_f32_16x16x32_bf16(al[mi].b, bh[ni].b, acc[mi][ni], 0, 0, 0);
                acc[mi][ni] = __builtin_amdgcn_mfma_f32_16x16x32_bf16(ah[mi].b, bl[ni].b, acc[mi][ni], 0, 0, 0);
                acc[mi][ni] = __builtin_amdgcn_mfma_f32_16x16x32_bf16(am[mi].b, bm[ni].b, acc[mi][ni], 0, 0, 0);
                acc[mi][ni] = __builtin_amdgcn_mfma_f32_16x16x32_bf16(am[mi].b, bh[ni].b, acc[mi][ni], 0, 0, 0);
                acc[mi][ni] = __builtin_amdgcn_mfma_f32_16x16x32_bf16(ah[mi].b, bm[ni].b, acc[mi][ni], 0, 0, 0);
                acc[mi][ni] = __builtin_amdgcn_mfma_f32_16x16x32_bf16(ah[mi].b, bh[ni].b, acc[mi][ni], 0, 0, 0);
            }
        __syncthreads();
    }

    #pragma unroll
    for (int ni = 0; ni < 4; ++ni) {
        int col = n0 + wn + ni * 16 + l16;
        float bv = biasf[col];
        #pragma unroll
        for (int mi = 0; mi < 4; ++mi) {
            int row = m0 + wm + mi * 16 + quad * 4;
            #pragma unroll
            for (int r = 0; r < 4; ++r)
                M[(size_t)(row + r) * N + col] = acc[mi][ni][r] + bv;
        }
    }
}

// ---------------------------------------------------------------------------
// Fallback tridiag: full-M input with in-kernel symmetrization (old version).
// ---------------------------------------------------------------------------
__global__ __launch_bounds__(64, 2) void tridiag_full(const float* __restrict__ M,
                                                      const float* __restrict__ regf,
                                                      double* __restrict__ trid)
{
    __shared__ float Ms[64][65];
    __shared__ __align__(16) double rowb[64];
    __shared__ __align__(16) double ubuf[64];
    __shared__ __align__(16) double wbuf[64];
    __shared__ double dbuf[64];
    __shared__ double ebuf[64];

    int g = blockIdx.x;
    int t = threadIdx.x;
    const float* Mg = M + (size_t)g * 4096;

    for (int r = 0; r < 64; ++r)
        Ms[r][t] = Mg[r * 64 + t];
    __syncthreads();

    double regv = (double)regf[0];
    double A[64];
    #pragma unroll
    for (int j = 0; j < 64; ++j)
        A[j] = 0.5 * ((double)Ms[t][j] + (double)Ms[j][t]);
    #pragma unroll
    for (int j = 0; j < 64; ++j)
        A[j] += (j == t) ? regv : 0.0;

    #pragma unroll 1
    for (int k = 0; k < 62; ++k) {
        if (t == k) {
            #pragma unroll
            for (int j = 0; j < 32; ++j)
                *(double2*)&rowb[2 * j] = double2{A[2 * j], A[2 * j + 1]};
        }
        __syncthreads();

        double s0 = 0.0, s1 = 0.0;
        #pragma unroll
        for (int j = 0; j < 64; ++j) {
            double aj = (j > k) ? A[j] : 0.0;
            if (j & 1) s1 += aj * aj; else s0 += aj * aj;
        }
        double sigma = __shfl(s0 + s1, k, 64);
        double x  = rowb[t];
        double x1 = __shfl(x, k + 1, 64);

        double alpha = 0.0, u = 0.0, w = 0.0, Kh = 1.0;
        bool run = (sigma > 1e-300);
        if (run) {
            double sq = sqrt(sigma);
            alpha = (x1 >= 0.0) ? -sq : sq;
            Kh = sigma - x1 * alpha;
            u = (t == k + 1) ? (x - alpha) : ((t > k) ? x : 0.0);
        }
        ubuf[t] = u;
        if (t == 0) { dbuf[k] = rowb[k]; ebuf[k] = alpha; }
        __syncthreads();

        if (run) {
            double p0 = 0.0, p1 = 0.0;
            #pragma unroll
            for (int j = 0; j < 32; ++j) {
                double2 uv = *(const double2*)&ubuf[2 * j];
                p0 += A[2 * j]     * uv.x;
                p1 += A[2 * j + 1] * uv.y;
            }
            double p = (t > k) ? (p0 + p1) / Kh : 0.0;
            double cc = wsum(u * p) / (2.0 * Kh);
            w = p - cc * u;
        }
        wbuf[t] = w;
        __syncthreads();

        if (run) {
            #pragma unroll
            for (int j = 0; j < 32; ++j) {
                double2 uv = *(const double2*)&ubuf[2 * j];
                double2 wv = *(const double2*)&wbuf[2 * j];
                A[2 * j]     -= u * wv.x + w * uv.x;
                A[2 * j + 1] -= u * wv.y + w * uv.y;
            }
        }
        __syncthreads();
    }

    if (t == 62) dbuf[62] = A[62];
    if (t == 63) { dbuf[63] = A[63]; ebuf[62] = A[62]; }
    if (t == 0)  ebuf[63] = 0.0;
    __syncthreads();

    double* tg = trid + (size_t)g * 128;
    tg[t]      = dbuf[t];
    tg[64 + t] = ebuf[t];
}

// ---------------------------------------------------------------------------
extern "C" void kernel_launch(void* const* d_in, const int* in_sizes, int n_in,
                              void* d_out, int out_size, void* d_ws, size_t ws_size,
                              hipStream_t stream)
{
    const float* X    = (const float*)d_in[0]; // [2048,2048] fp32
    const float* Wt   = (const float*)d_in[1]; // [4096,2048] fp32
    const float* bias = (const float*)d_in[2]; // [4096] fp32
    const float* regp = (const float*)d_in[3]; // [1] fp32

    char* w = (char*)d_ws;
    float* out = (float*)d_out;                          // [2048,64] fp32

    const size_t NEED_FAST = 87826688ull;
    if (ws_size >= NEED_FAST) {
        float*  Mp   = (float*)w;                        // 2x 2048x2112 fp32 (split-K halves)
        double* trid = (double*)(w + 34603008);          // 2 MB
        unsigned short* Xh = (unsigned short*)(w + 36700160);
        unsigned short* Xm = (unsigned short*)(w + 45088768);
        unsigned short* Xl = (unsigned short*)(w + 53477376);
        unsigned short* Sh = (unsigned short*)(w + 61865984);
        unsigned short* Sm = (unsigned short*)(w + 70516736);
        unsigned short* Sl = (unsigned short*)(w + 79167488);
        float* bsym = (float*)(w + 87818240);            // 2112 fp32
        split2<<<dim3(8320), dim3(256), 0, stream>>>(X, Wt, bias, regp,
                                                     Xh, Xm, Xl, Sh, Sm, Sl, bsym);
        gemm_packed<<<dim3(1056), dim3(256), 0, stream>>>(Xh, Xm, Xl, Sh, Sm, Sl, bsym, Mp);
        tridiag_packed4<<<dim3(2048), dim3(128), 0, stream>>>(Mp, trid);
        bisect_kernel<<<dim3(2048), dim3(64), 0, stream>>>(trid, out);
    } else {
        float*  M    = (float*)w;                        // 32 MB
        double* trid = (double*)(w + 33554432);          // 2 MB
        gemm_bt<<<dim3(32, 16), dim3(256), 0, stream>>>(X, Wt, bias, M);
        tridiag_full<<<dim3(2048), dim3(64), 0, stream>>>(M, regp, trid);
        bisect_kernel<<<dim3(2048), dim3(64), 0, stream>>>(trid, out);
    }
}